// Round 8
// baseline (650.399 us; speedup 1.0000x reference)
//
#include <hip/hip_runtime.h>
#include <hip/hip_bf16.h>

#define Nn 100000
#define Ee 1600000
#define Hh 128
#define Gg 1000
#define EPSb 1e-5f

#define SCAN_CHUNK 1024
#define NB_SCAN 98          // ceil(100000/1024)
#define AGG_BLOCKS 2048
#define NWAVES (AGG_BLOCKS * 4)   // 8192
#define GEMM_BLOCKS 782     // ceil(100000/128)

typedef unsigned int uint;
typedef short short8 __attribute__((ext_vector_type(8)));
typedef float floatx4 __attribute__((ext_vector_type(4)));

// round-to-nearest-even f32 -> bf16 (as low 16 bits of return)
static __device__ __forceinline__ uint bf16rne(float f) {
    uint u = __float_as_uint(f);
    return (u + 0x7fffu + ((u >> 16) & 1u)) >> 16;
}
static __device__ __forceinline__ float bflo(uint u) { return __uint_as_float(u << 16); }
static __device__ __forceinline__ float bfhi(uint u) { return __uint_as_float(u & 0xffff0000u); }

// ---------------- graph preprocessing ----------------

__global__ void k_init(int* __restrict__ deg, int* __restrict__ cursor,
                       float* __restrict__ colsum) {
    int i = blockIdx.x * blockDim.x + threadIdx.x;
    if (i < Nn) { deg[i] = 1; cursor[i] = 0; }
    if (i < 768) colsum[i] = 0.f;   // 3 layers x (sum[128], sumsq[128])
}

__global__ void k_deg(const int* __restrict__ dst, int* __restrict__ deg) {
    int i = blockIdx.x * blockDim.x + threadIdx.x;
    if (i < Ee) atomicAdd(&deg[dst[i]], 1);
}

__global__ void k_scan1(const int* __restrict__ deg, int* __restrict__ bsum) {
    __shared__ int ls[256];
    int t = threadIdx.x;
    int base = blockIdx.x * SCAN_CHUNK + t * 4;
    int s = 0;
#pragma unroll
    for (int j = 0; j < 4; ++j) { int i = base + j; if (i < Nn) s += deg[i]; }
    ls[t] = s;
    __syncthreads();
    for (int off = 128; off; off >>= 1) {
        if (t < off) ls[t] += ls[t + off];
        __syncthreads();
    }
    if (t == 0) bsum[blockIdx.x] = ls[0];
}

// parallel exclusive scan over NB_SCAN block sums (single block, 128 thr)
__global__ void k_scan2(int* __restrict__ bsum) {
    __shared__ int ls[128];
    int t = threadIdx.x;
    int v = (t < NB_SCAN) ? bsum[t] : 0;
    ls[t] = v;
    __syncthreads();
    for (int off = 1; off < 128; off <<= 1) {
        int u = (t >= off) ? ls[t - off] : 0;
        __syncthreads();
        ls[t] += u;
        __syncthreads();
    }
    if (t < NB_SCAN) bsum[t] = ls[t] - v;
}

// scan3 also emits dinv (folded k_dinv)
__global__ void k_scan3(const int* __restrict__ deg, const int* __restrict__ bsum,
                        int* __restrict__ offs, float* __restrict__ dinv) {
    __shared__ int ls[256];
    int t = threadIdx.x;
    int base = blockIdx.x * SCAN_CHUNK + t * 4;
    int d[4]; int s = 0;
#pragma unroll
    for (int j = 0; j < 4; ++j) {
        int i = base + j;
        d[j] = (i < Nn) ? deg[i] : 0;
        s += d[j];
    }
    ls[t] = s;
    __syncthreads();
    for (int off = 1; off < 256; off <<= 1) {
        int u = (t >= off) ? ls[t - off] : 0;
        __syncthreads();
        ls[t] += u;
        __syncthreads();
    }
    int run = bsum[blockIdx.x] + ls[t] - s;   // exclusive prefix for this thread
#pragma unroll
    for (int j = 0; j < 4; ++j) {
        int i = base + j;
        if (i < Nn) {
            offs[i] = run;
            dinv[i] = rsqrtf((float)d[j]);
        }
        run += d[j];
    }
    if (blockIdx.x == 0 && t == 0) offs[Nn] = Ee + Nn;
}

__global__ void k_fill(const int* __restrict__ src, const int* __restrict__ dst,
                       const int* __restrict__ offs, int* __restrict__ cursor,
                       const float* __restrict__ dinv,
                       int2* __restrict__ adj) {
    int i = blockIdx.x * blockDim.x + threadIdx.x;
    if (i >= Ee + Nn) return;
    int s, d;
    if (i < Ee) { s = src[i]; d = dst[i]; }
    else        { s = d = i - Ee; }
    int pos = offs[d] + atomicAdd(&cursor[d], 1);
    adj[pos] = make_int2(s, __float_as_int(dinv[s] * dinv[d]));
}

// ------- W conversion (all 3 layers): Wt[l][n][k/2] = bf16(W[k][n],W[k+1][n]) --

__global__ void k_wconv3(const float* __restrict__ W1, const float* __restrict__ W2,
                         const float* __restrict__ W3, uint* __restrict__ Wt) {
    int idx = blockIdx.x * blockDim.x + threadIdx.x;   // 3*8192
    if (idx >= 3 * 8192) return;
    const float* W = (idx < 8192) ? W1 : ((idx < 16384) ? W2 : W3);
    int k = idx & 8191;
    int n = k >> 6, ku = k & 63;
    uint lo = bf16rne(W[(size_t)(2 * ku) * 128 + n]);
    uint hi = bf16rne(W[(size_t)(2 * ku + 1) * 128 + n]);
    Wt[(size_t)(idx >> 13) * 8192 + n * 64 + ku] = lo | (hi << 16);
}

// ---------------- MFMA GEMM: tmp(bf16) = act(in) @ W ----------------------
// mode 0: in = fp32 x (row-major), identity activation.
// mode 1: in = row-major packed-bf16 agg; activation = relu(bn(v)) where the
// BN affine (scale/shift) is computed in-block from colsum + gamma + beta.

__global__ __launch_bounds__(256) void k_gemm(
    const float* __restrict__ inf, const uint* __restrict__ inb,
    const uint* __restrict__ Wtp,
    const float* __restrict__ cs, const float* __restrict__ gg,
    const float* __restrict__ be,
    uint* __restrict__ outb, int mode) {
    __shared__ uint XT[128][64];
    __shared__ uint WT[128][64];
    __shared__ float scsh[256];   // sc[128], sh[128]
    int t = threadIdx.x;
    int rowBase = blockIdx.x * 128;
    int r = t >> 1, half = t & 1;

    if (mode) {
        if (t < 128) {
            float s = cs[t], q = cs[128 + t];
            float m = s * (1.0f / Nn);
            float var = q * (1.0f / Nn) - m * m;
            float istd = rsqrtf(var + EPSb);
            float sc = istd * gg[t];
            scsh[t] = sc;
            scsh[128 + t] = fmaf(-m, sc, be[t]);
        }
        __syncthreads();
    }

    {   // stage activations
        int gr = rowBase + r;
        int grc = gr < Nn ? gr : Nn - 1;
        if (mode == 0) {
            const float* sp = inf + (size_t)grc * 128 + half * 64;
#pragma unroll
            for (int q = 0; q < 8; ++q) {
                float4 v0 = *(const float4*)(sp + q * 8);
                float4 v1 = *(const float4*)(sp + q * 8 + 4);
                uint4 o;
                o.x = bf16rne(v0.x) | (bf16rne(v0.y) << 16);
                o.y = bf16rne(v0.z) | (bf16rne(v0.w) << 16);
                o.z = bf16rne(v1.x) | (bf16rne(v1.y) << 16);
                o.w = bf16rne(v1.z) | (bf16rne(v1.w) << 16);
                int g = half * 8 + q;
                *(uint4*)&XT[r][(g ^ (r & 7)) << 2] = o;
            }
        } else {
            const uint* sp = inb + (size_t)grc * 64 + half * 32;
#pragma unroll
            for (int q = 0; q < 8; ++q) {
                uint4 v = *(const uint4*)(sp + q * 4);
                int fb = half * 64 + q * 8;
                float av[8] = {bflo(v.x), bfhi(v.x), bflo(v.y), bfhi(v.y),
                               bflo(v.z), bfhi(v.z), bflo(v.w), bfhi(v.w)};
                uint o[4];
#pragma unroll
                for (int k2 = 0; k2 < 4; ++k2) {
                    float lo = fmaxf(fmaf(av[2 * k2], scsh[fb + 2 * k2],
                                          scsh[128 + fb + 2 * k2]), 0.f);
                    float hi = fmaxf(fmaf(av[2 * k2 + 1], scsh[fb + 2 * k2 + 1],
                                          scsh[128 + fb + 2 * k2 + 1]), 0.f);
                    o[k2] = bf16rne(lo) | (bf16rne(hi) << 16);
                }
                uint4 ov = make_uint4(o[0], o[1], o[2], o[3]);
                int g = half * 8 + q;
                *(uint4*)&XT[r][(g ^ (r & 7)) << 2] = ov;
            }
        }
    }
    {   // stage W^T (already packed bf16)
        const uint* sp = Wtp + (size_t)r * 64 + half * 32;
#pragma unroll
        for (int q = 0; q < 8; ++q) {
            uint4 v = *(const uint4*)(sp + q * 4);
            int g = half * 8 + q;
            *(uint4*)&WT[r][(g ^ (r & 7)) << 2] = v;
        }
    }
    __syncthreads();

    int l = t & 63, w = t >> 6;
    int nb = (w >> 1) * 64;       // node-tile base
    int fb2 = (w & 1) * 64;       // feature-tile base
    int lr = l & 15, lk = l >> 4;
    floatx4 zero = {0.f, 0.f, 0.f, 0.f};
    floatx4 acc[4][4];
#pragma unroll
    for (int mi = 0; mi < 4; ++mi)
#pragma unroll
        for (int ni = 0; ni < 4; ++ni) acc[mi][ni] = zero;

#pragma unroll
    for (int kc = 0; kc < 4; ++kc) {
        short8 xf[4], wf[4];
        int g = kc * 4 + lk;
#pragma unroll
        for (int mi = 0; mi < 4; ++mi) {
            int rr = nb + mi * 16 + lr;
            xf[mi] = *(const short8*)&XT[rr][(g ^ (rr & 7)) << 2];
        }
#pragma unroll
        for (int ni = 0; ni < 4; ++ni) {
            int rr = fb2 + ni * 16 + lr;
            wf[ni] = *(const short8*)&WT[rr][(g ^ (rr & 7)) << 2];
        }
#pragma unroll
        for (int mi = 0; mi < 4; ++mi)
#pragma unroll
            for (int ni = 0; ni < 4; ++ni)
                acc[mi][ni] = __builtin_amdgcn_mfma_f32_16x16x32_bf16(
                    wf[ni], xf[mi], acc[mi][ni], 0, 0, 0);
    }

    // epilogue: D col(lane&15)=node, row((lane>>4)*4+reg)=feature
#pragma unroll
    for (int mi = 0; mi < 4; ++mi) {
        int node = rowBase + nb + mi * 16 + lr;
        if (node < Nn) {
            uint* op = outb + (size_t)node * 64;
#pragma unroll
            for (int ni = 0; ni < 4; ++ni) {
                int fo = fb2 + ni * 16 + lk * 4;
                uint2 o;
                o.x = bf16rne(acc[mi][ni][0]) | (bf16rne(acc[mi][ni][1]) << 16);
                o.y = bf16rne(acc[mi][ni][2]) | (bf16rne(acc[mi][ni][3]) << 16);
                *(uint2*)(op + (fo >> 1)) = o;
            }
        }
    }
}

// ------- aggregation: agg[d] = sum_e w*h[src] + bias; BN partials -------
// Dual-node version: each wave processes node pair (d, d+NWAVES) per outer
// iteration. Wave-uniform control flow; the co-iterated chunk loop keeps
// 16 independent row-gathers in flight (2x the single-node loop's MLP).

__global__ __launch_bounds__(256) void k_agg(
    const uint* __restrict__ h32, const int* __restrict__ offs,
    const int2* __restrict__ adj,
    const float* __restrict__ bias, uint* __restrict__ agg,
    float* __restrict__ colsum) {
    __shared__ float ls[256];
    int tid = threadIdx.x;
    ls[tid] = 0.f;
    __syncthreads();
    int lane = tid & 63;
    int wi = blockIdx.x * 4 + (tid >> 6);
    int c0 = lane * 2;
    float bb0 = bias[c0], bb1 = bias[c0 + 1];
    float ps0 = 0.f, pq0 = 0.f, ps1 = 0.f, pq1 = 0.f;
    for (int d0 = wi; d0 < Nn; d0 += 2 * NWAVES) {
        int dA = d0;
        int dB = d0 + NWAVES;
        int hasB = (dB < Nn);
        int begA = offs[dA], endA = offs[dA + 1];
        int begB = 0, endB = 0;
        if (hasB) { begB = offs[dB]; endB = offs[dB + 1]; }
        float a0 = 0.f, a1 = 0.f, b0 = 0.f, b1 = 0.f;
        int ia = begA, ib = begB;
        int ncA = (endA - ia) >> 3, ncB = (endB - ib) >> 3;
        int nmin = ncA < ncB ? ncA : ncB;
        for (int c = 0; c < nmin; ++c) {
            int2 eA[8], eB[8];
#pragma unroll
            for (int j = 0; j < 8; ++j) eA[j] = adj[ia + j];
#pragma unroll
            for (int j = 0; j < 8; ++j) eB[j] = adj[ib + j];
            uint hA[8], hB[8];
#pragma unroll
            for (int j = 0; j < 8; ++j) hA[j] = h32[(size_t)eA[j].x * 64 + lane];
#pragma unroll
            for (int j = 0; j < 8; ++j) hB[j] = h32[(size_t)eB[j].x * 64 + lane];
#pragma unroll
            for (int j = 0; j < 8; ++j) {
                float w = __int_as_float(eA[j].y);
                a0 = fmaf(w, bflo(hA[j]), a0);
                a1 = fmaf(w, bfhi(hA[j]), a1);
            }
#pragma unroll
            for (int j = 0; j < 8; ++j) {
                float w = __int_as_float(eB[j].y);
                b0 = fmaf(w, bflo(hB[j]), b0);
                b1 = fmaf(w, bfhi(hB[j]), b1);
            }
            ia += 8; ib += 8;
        }
        for (int c = nmin; c < ncA; ++c) {
            int2 e[8];
#pragma unroll
            for (int j = 0; j < 8; ++j) e[j] = adj[ia + j];
            uint hv[8];
#pragma unroll
            for (int j = 0; j < 8; ++j) hv[j] = h32[(size_t)e[j].x * 64 + lane];
#pragma unroll
            for (int j = 0; j < 8; ++j) {
                float w = __int_as_float(e[j].y);
                a0 = fmaf(w, bflo(hv[j]), a0);
                a1 = fmaf(w, bfhi(hv[j]), a1);
            }
            ia += 8;
        }
        for (int c = nmin; c < ncB; ++c) {
            int2 e[8];
#pragma unroll
            for (int j = 0; j < 8; ++j) e[j] = adj[ib + j];
            uint hv[8];
#pragma unroll
            for (int j = 0; j < 8; ++j) hv[j] = h32[(size_t)e[j].x * 64 + lane];
#pragma unroll
            for (int j = 0; j < 8; ++j) {
                float w = __int_as_float(e[j].y);
                b0 = fmaf(w, bflo(hv[j]), b0);
                b1 = fmaf(w, bfhi(hv[j]), b1);
            }
            ib += 8;
        }
        for (; ia < endA; ++ia) {
            int2 e = adj[ia];
            uint hv = h32[(size_t)e.x * 64 + lane];
            float w = __int_as_float(e.y);
            a0 = fmaf(w, bflo(hv), a0);
            a1 = fmaf(w, bfhi(hv), a1);
        }
        for (; ib < endB; ++ib) {
            int2 e = adj[ib];
            uint hv = h32[(size_t)e.x * 64 + lane];
            float w = __int_as_float(e.y);
            b0 = fmaf(w, bflo(hv), b0);
            b1 = fmaf(w, bfhi(hv), b1);
        }
        a0 += bb0; a1 += bb1;
        agg[(size_t)dA * 64 + lane] = bf16rne(a0) | (bf16rne(a1) << 16);
        ps0 += a0; pq0 += a0 * a0;
        ps1 += a1; pq1 += a1 * a1;
        if (hasB) {
            b0 += bb0; b1 += bb1;
            agg[(size_t)dB * 64 + lane] = bf16rne(b0) | (bf16rne(b1) << 16);
            ps0 += b0; pq0 += b0 * b0;
            ps1 += b1; pq1 += b1 * b1;
        }
    }
    atomicAdd(&ls[c0], ps0);
    atomicAdd(&ls[c0 + 1], ps1);
    atomicAdd(&ls[128 + c0], pq0);
    atomicAdd(&ls[128 + c0 + 1], pq1);
    __syncthreads();
    atomicAdd(&colsum[tid], ls[tid]);
}

// ---------------- pool + linear (BN affine computed in-block) -------------

__global__ __launch_bounds__(256) void k_pool(
    const uint* __restrict__ agg, const int* __restrict__ batch,
    const float* __restrict__ cs, const float* __restrict__ gg,
    const float* __restrict__ be,
    const float* __restrict__ Wl, const float* __restrict__ bl,
    float* __restrict__ out) {
    __shared__ float scsh[256];
    int tid = threadIdx.x;
    if (tid < 128) {
        float s = cs[tid], q = cs[128 + tid];
        float m = s * (1.0f / Nn);
        float var = q * (1.0f / Nn) - m * m;
        float istd = rsqrtf(var + EPSb);
        float sc = istd * gg[tid];
        scsh[tid] = sc;
        scsh[128 + tid] = fmaf(-m, sc, be[tid]);
    }
    __syncthreads();
    int lane = tid & 63;
    int g = (blockIdx.x * blockDim.x + tid) >> 6;
    if (g >= Gg) return;
    int lo = 0, hi = Nn;
    while (lo < hi) { int mid = (lo + hi) >> 1; if (batch[mid] < g) lo = mid + 1; else hi = mid; }
    int beg = lo;
    hi = Nn;
    while (lo < hi) { int mid = (lo + hi) >> 1; if (batch[mid] < g + 1) lo = mid + 1; else hi = mid; }
    int end = lo;
    int c0 = lane * 2;
    float sc0 = scsh[c0], sh0 = scsh[128 + c0];
    float sc1 = scsh[c0 + 1], sh1 = scsh[128 + c0 + 1];
    float s0 = 0.f, s1 = 0.f;
    for (int n = beg; n < end; ++n) {
        uint v = agg[(size_t)n * 64 + lane];
        s0 += fmaxf(fmaf(bflo(v), sc0, sh0), 0.f);
        s1 += fmaxf(fmaf(bfhi(v), sc1, sh1), 0.f);
    }
    float inv = 1.0f / fmaxf((float)(end - beg), 1.0f);
    float part = (s0 * inv) * Wl[c0] + (s1 * inv) * Wl[c0 + 1];
#pragma unroll
    for (int off = 32; off; off >>= 1) part += __shfl_down(part, off);
    if (lane == 0) out[g] = part + bl[0];
}

// ---------------- launch --------------------------------------------------

extern "C" void kernel_launch(void* const* d_in, const int* in_sizes, int n_in,
                              void* d_out, int out_size, void* d_ws, size_t ws_size,
                              hipStream_t stream) {
    const float* x   = (const float*)d_in[0];
    const int*   ei  = (const int*)d_in[1];
    const int*   src = ei;
    const int*   dst = ei + Ee;
    const int*   bat = (const int*)d_in[2];
    const float* W1 = (const float*)d_in[3];
    const float* b1 = (const float*)d_in[4];
    const float* g1 = (const float*)d_in[5];
    const float* be1 = (const float*)d_in[6];
    const float* W2 = (const float*)d_in[7];
    const float* b2 = (const float*)d_in[8];
    const float* g2 = (const float*)d_in[9];
    const float* be2 = (const float*)d_in[10];
    const float* W3 = (const float*)d_in[11];
    const float* b3 = (const float*)d_in[12];
    const float* g3 = (const float*)d_in[13];
    const float* be3 = (const float*)d_in[14];
    const float* Wl = (const float*)d_in[15];
    const float* bl = (const float*)d_in[16];
    float* out = (float*)d_out;

    char* w = (char*)d_ws;
    auto alloc = [&](size_t bytes) {
        void* p = (void*)w;
        w += (bytes + 255) & ~(size_t)255;
        return p;
    };
    int*   deg    = (int*)alloc((size_t)Nn * 4);
    int*   cursor = (int*)alloc((size_t)Nn * 4);
    int*   offs   = (int*)alloc((size_t)(Nn + 1) * 4);
    int*   bsum   = (int*)alloc(256 * 4);
    float* dinv   = (float*)alloc((size_t)Nn * 4);
    float* colsum = (float*)alloc(768 * 4);   // 3 layers x 256
    uint*  Wt     = (uint*)alloc((size_t)3 * 8192 * 4);
    int2*  adj    = (int2*)alloc((size_t)(Ee + Nn) * 8);
    uint*  tmp    = (uint*)alloc((size_t)Nn * 64 * 4);   // bf16-packed h
    uint*  agg    = (uint*)alloc((size_t)Nn * 64 * 4);   // bf16-packed agg

    float* csA = colsum;        // stats of agg1 (uses g1/be1)
    float* csB = colsum + 256;  // stats of agg2 (uses g2/be2)
    float* csC = colsum + 512;  // stats of agg3 (uses g3/be3)

    // graph preprocessing + weight conversion
    k_init<<<(Nn + 255) / 256, 256, 0, stream>>>(deg, cursor, colsum);
    k_deg<<<(Ee + 255) / 256, 256, 0, stream>>>(dst, deg);
    k_scan1<<<NB_SCAN, 256, 0, stream>>>(deg, bsum);
    k_scan2<<<1, 128, 0, stream>>>(bsum);
    k_scan3<<<NB_SCAN, 256, 0, stream>>>(deg, bsum, offs, dinv);
    k_fill<<<(Ee + Nn + 255) / 256, 256, 0, stream>>>(src, dst, offs, cursor, dinv, adj);
    k_wconv3<<<96, 256, 0, stream>>>(W1, W2, W3, Wt);
    // layer 1
    k_gemm<<<GEMM_BLOCKS, 256, 0, stream>>>(x, (const uint*)0, Wt,
                                            (const float*)0, (const float*)0,
                                            (const float*)0, tmp, 0);
    k_agg<<<AGG_BLOCKS, 256, 0, stream>>>(tmp, offs, adj, b1, agg, csA);
    // layer 2
    k_gemm<<<GEMM_BLOCKS, 256, 0, stream>>>((const float*)0, agg, Wt + 8192,
                                            csA, g1, be1, tmp, 1);
    k_agg<<<AGG_BLOCKS, 256, 0, stream>>>(tmp, offs, adj, b2, agg, csB);
    // layer 3
    k_gemm<<<GEMM_BLOCKS, 256, 0, stream>>>((const float*)0, agg, Wt + 16384,
                                            csB, g2, be2, tmp, 1);
    k_agg<<<AGG_BLOCKS, 256, 0, stream>>>(tmp, offs, adj, b3, agg, csC);
    // pool + linear
    k_pool<<<(Gg * 64 + 255) / 256, 256, 0, stream>>>(agg, bat, csC, g3, be3,
                                                      Wl, bl, out);
}

// Round 9
// 647.549 us; speedup vs baseline: 1.0044x; 1.0044x over previous
//
#include <hip/hip_runtime.h>
#include <hip/hip_bf16.h>

#define Nn 100000
#define Ee 1600000
#define Hh 128
#define Gg 1000
#define EPSb 1e-5f

#define SCAN_CHUNK 1024
#define NB_SCAN 98          // ceil(100000/1024)
#define AGG_BLOCKS 2048
#define NWAVES (AGG_BLOCKS * 4)   // 8192
#define GEMM_BLOCKS 782     // ceil(100000/128)

typedef unsigned int uint;
typedef unsigned long long u64;
typedef short short8 __attribute__((ext_vector_type(8)));
typedef float floatx4 __attribute__((ext_vector_type(4)));

// round-to-nearest-even f32 -> bf16 (as low 16 bits of return)
static __device__ __forceinline__ uint bf16rne(float f) {
    uint u = __float_as_uint(f);
    return (u + 0x7fffu + ((u >> 16) & 1u)) >> 16;
}
static __device__ __forceinline__ float bflo(uint u) { return __uint_as_float(u << 16); }
static __device__ __forceinline__ float bfhi(uint u) { return __uint_as_float(u & 0xffff0000u); }

// ---------------- graph preprocessing ----------------

__global__ void k_init(int* __restrict__ deg, int* __restrict__ cursor,
                       float* __restrict__ colsum) {
    int i = blockIdx.x * blockDim.x + threadIdx.x;
    if (i < Nn) { deg[i] = 1; cursor[i] = 0; }
    if (i < 768) colsum[i] = 0.f;   // 3 layers x (sum[128], sumsq[128])
}

__global__ void k_deg(const int* __restrict__ dst, int* __restrict__ deg) {
    int i = blockIdx.x * blockDim.x + threadIdx.x;
    if (i < Ee) atomicAdd(&deg[dst[i]], 1);
}

__global__ void k_scan1(const int* __restrict__ deg, int* __restrict__ bsum) {
    __shared__ int ls[256];
    int t = threadIdx.x;
    int base = blockIdx.x * SCAN_CHUNK + t * 4;
    int s = 0;
#pragma unroll
    for (int j = 0; j < 4; ++j) { int i = base + j; if (i < Nn) s += deg[i]; }
    ls[t] = s;
    __syncthreads();
    for (int off = 128; off; off >>= 1) {
        if (t < off) ls[t] += ls[t + off];
        __syncthreads();
    }
    if (t == 0) bsum[blockIdx.x] = ls[0];
}

// parallel exclusive scan over NB_SCAN block sums (single block, 128 thr)
__global__ void k_scan2(int* __restrict__ bsum) {
    __shared__ int ls[128];
    int t = threadIdx.x;
    int v = (t < NB_SCAN) ? bsum[t] : 0;
    ls[t] = v;
    __syncthreads();
    for (int off = 1; off < 128; off <<= 1) {
        int u = (t >= off) ? ls[t - off] : 0;
        __syncthreads();
        ls[t] += u;
        __syncthreads();
    }
    if (t < NB_SCAN) bsum[t] = ls[t] - v;
}

// scan3 also emits dinv (folded k_dinv)
__global__ void k_scan3(const int* __restrict__ deg, const int* __restrict__ bsum,
                        int* __restrict__ offs, float* __restrict__ dinv) {
    __shared__ int ls[256];
    int t = threadIdx.x;
    int base = blockIdx.x * SCAN_CHUNK + t * 4;
    int d[4]; int s = 0;
#pragma unroll
    for (int j = 0; j < 4; ++j) {
        int i = base + j;
        d[j] = (i < Nn) ? deg[i] : 0;
        s += d[j];
    }
    ls[t] = s;
    __syncthreads();
    for (int off = 1; off < 256; off <<= 1) {
        int u = (t >= off) ? ls[t - off] : 0;
        __syncthreads();
        ls[t] += u;
        __syncthreads();
    }
    int run = bsum[blockIdx.x] + ls[t] - s;   // exclusive prefix for this thread
#pragma unroll
    for (int j = 0; j < 4; ++j) {
        int i = base + j;
        if (i < Nn) {
            offs[i] = run;
            dinv[i] = rsqrtf((float)d[j]);
        }
        run += d[j];
    }
    if (blockIdx.x == 0 && t == 0) offs[Nn] = Ee + Nn;
}

__global__ void k_fill(const int* __restrict__ src, const int* __restrict__ dst,
                       const int* __restrict__ offs, int* __restrict__ cursor,
                       const float* __restrict__ dinv,
                       int2* __restrict__ adj) {
    int i = blockIdx.x * blockDim.x + threadIdx.x;
    if (i >= Ee + Nn) return;
    int s, d;
    if (i < Ee) { s = src[i]; d = dst[i]; }
    else        { s = d = i - Ee; }
    int pos = offs[d] + atomicAdd(&cursor[d], 1);
    adj[pos] = make_int2(s, __float_as_int(dinv[s] * dinv[d]));
}

// ------- W conversion (all 3 layers): Wt[l][n][k/2] = bf16(W[k][n],W[k+1][n]) --

__global__ void k_wconv3(const float* __restrict__ W1, const float* __restrict__ W2,
                         const float* __restrict__ W3, uint* __restrict__ Wt) {
    int idx = blockIdx.x * blockDim.x + threadIdx.x;   // 3*8192
    if (idx >= 3 * 8192) return;
    const float* W = (idx < 8192) ? W1 : ((idx < 16384) ? W2 : W3);
    int k = idx & 8191;
    int n = k >> 6, ku = k & 63;
    uint lo = bf16rne(W[(size_t)(2 * ku) * 128 + n]);
    uint hi = bf16rne(W[(size_t)(2 * ku + 1) * 128 + n]);
    Wt[(size_t)(idx >> 13) * 8192 + n * 64 + ku] = lo | (hi << 16);
}

// ---------------- MFMA GEMM: tmp(bf16) = act(in) @ W ----------------------
// mode 0: in = fp32 x (row-major), identity activation.
// mode 1: in = row-major packed-bf16 agg; activation = relu(bn(v)) where the
// BN affine (scale/shift) is computed in-block from colsum + gamma + beta.

__global__ __launch_bounds__(256) void k_gemm(
    const float* __restrict__ inf, const uint* __restrict__ inb,
    const uint* __restrict__ Wtp,
    const float* __restrict__ cs, const float* __restrict__ gg,
    const float* __restrict__ be,
    uint* __restrict__ outb, int mode) {
    __shared__ uint XT[128][64];
    __shared__ uint WT[128][64];
    __shared__ float scsh[256];   // sc[128], sh[128]
    int t = threadIdx.x;
    int rowBase = blockIdx.x * 128;
    int r = t >> 1, half = t & 1;

    if (mode) {
        if (t < 128) {
            float s = cs[t], q = cs[128 + t];
            float m = s * (1.0f / Nn);
            float var = q * (1.0f / Nn) - m * m;
            float istd = rsqrtf(var + EPSb);
            float sc = istd * gg[t];
            scsh[t] = sc;
            scsh[128 + t] = fmaf(-m, sc, be[t]);
        }
        __syncthreads();
    }

    {   // stage activations
        int gr = rowBase + r;
        int grc = gr < Nn ? gr : Nn - 1;
        if (mode == 0) {
            const float* sp = inf + (size_t)grc * 128 + half * 64;
#pragma unroll
            for (int q = 0; q < 8; ++q) {
                float4 v0 = *(const float4*)(sp + q * 8);
                float4 v1 = *(const float4*)(sp + q * 8 + 4);
                uint4 o;
                o.x = bf16rne(v0.x) | (bf16rne(v0.y) << 16);
                o.y = bf16rne(v0.z) | (bf16rne(v0.w) << 16);
                o.z = bf16rne(v1.x) | (bf16rne(v1.y) << 16);
                o.w = bf16rne(v1.z) | (bf16rne(v1.w) << 16);
                int g = half * 8 + q;
                *(uint4*)&XT[r][(g ^ (r & 7)) << 2] = o;
            }
        } else {
            const uint* sp = inb + (size_t)grc * 64 + half * 32;
#pragma unroll
            for (int q = 0; q < 8; ++q) {
                uint4 v = *(const uint4*)(sp + q * 4);
                int fb = half * 64 + q * 8;
                float av[8] = {bflo(v.x), bfhi(v.x), bflo(v.y), bfhi(v.y),
                               bflo(v.z), bfhi(v.z), bflo(v.w), bfhi(v.w)};
                uint o[4];
#pragma unroll
                for (int k2 = 0; k2 < 4; ++k2) {
                    float lo = fmaxf(fmaf(av[2 * k2], scsh[fb + 2 * k2],
                                          scsh[128 + fb + 2 * k2]), 0.f);
                    float hi = fmaxf(fmaf(av[2 * k2 + 1], scsh[fb + 2 * k2 + 1],
                                          scsh[128 + fb + 2 * k2 + 1]), 0.f);
                    o[k2] = bf16rne(lo) | (bf16rne(hi) << 16);
                }
                uint4 ov = make_uint4(o[0], o[1], o[2], o[3]);
                int g = half * 8 + q;
                *(uint4*)&XT[r][(g ^ (r & 7)) << 2] = ov;
            }
        }
    }
    {   // stage W^T (already packed bf16)
        const uint* sp = Wtp + (size_t)r * 64 + half * 32;
#pragma unroll
        for (int q = 0; q < 8; ++q) {
            uint4 v = *(const uint4*)(sp + q * 4);
            int g = half * 8 + q;
            *(uint4*)&WT[r][(g ^ (r & 7)) << 2] = v;
        }
    }
    __syncthreads();

    int l = t & 63, w = t >> 6;
    int nb = (w >> 1) * 64;       // node-tile base
    int fb2 = (w & 1) * 64;       // feature-tile base
    int lr = l & 15, lk = l >> 4;
    floatx4 zero = {0.f, 0.f, 0.f, 0.f};
    floatx4 acc[4][4];
#pragma unroll
    for (int mi = 0; mi < 4; ++mi)
#pragma unroll
        for (int ni = 0; ni < 4; ++ni) acc[mi][ni] = zero;

#pragma unroll
    for (int kc = 0; kc < 4; ++kc) {
        short8 xf[4], wf[4];
        int g = kc * 4 + lk;
#pragma unroll
        for (int mi = 0; mi < 4; ++mi) {
            int rr = nb + mi * 16 + lr;
            xf[mi] = *(const short8*)&XT[rr][(g ^ (rr & 7)) << 2];
        }
#pragma unroll
        for (int ni = 0; ni < 4; ++ni) {
            int rr = fb2 + ni * 16 + lr;
            wf[ni] = *(const short8*)&WT[rr][(g ^ (rr & 7)) << 2];
        }
#pragma unroll
        for (int mi = 0; mi < 4; ++mi)
#pragma unroll
            for (int ni = 0; ni < 4; ++ni)
                acc[mi][ni] = __builtin_amdgcn_mfma_f32_16x16x32_bf16(
                    wf[ni], xf[mi], acc[mi][ni], 0, 0, 0);
    }

    // epilogue: D col(lane&15)=node, row((lane>>4)*4+reg)=feature
#pragma unroll
    for (int mi = 0; mi < 4; ++mi) {
        int node = rowBase + nb + mi * 16 + lr;
        if (node < Nn) {
            uint* op = outb + (size_t)node * 64;
#pragma unroll
            for (int ni = 0; ni < 4; ++ni) {
                int fo = fb2 + ni * 16 + lk * 4;
                uint2 o;
                o.x = bf16rne(acc[mi][ni][0]) | (bf16rne(acc[mi][ni][1]) << 16);
                o.y = bf16rne(acc[mi][ni][2]) | (bf16rne(acc[mi][ni][3]) << 16);
                *(uint2*)(op + (fo >> 1)) = o;
            }
        }
    }
}

// ------- aggregation: agg[d] = sum_e w*h[src] + bias; BN partials -------
// 4 row-groups x 16 lanes: each lane gathers uint4 (16B), so ONE gather
// instruction covers 4 edges' rows (4x fewer VMEM instrs than 1-edge/instr).
// Tail handled as masked 4-edge wave-parallel steps (no serial scalar loop).
// Epilogue: shfl_xor(16/32) group-reduce; lanes 0-15 add bias, pack bf16,
// one dwordx4 store, and own BN partials.

__global__ __launch_bounds__(256) void k_agg(
    const uint* __restrict__ h32, const int* __restrict__ offs,
    const int2* __restrict__ adj,
    const float* __restrict__ bias, uint* __restrict__ agg,
    float* __restrict__ colsum) {
    __shared__ float ls[256];
    int tid = threadIdx.x;
    ls[tid] = 0.f;
    __syncthreads();
    int lane = tid & 63;
    int g = lane >> 4;          // row-group 0..3
    int c = lane & 15;          // uint4 column within row
    int wv = blockIdx.x * 4 + (tid >> 6);
    const uint4* h4 = (const uint4*)h32;     // row = 16 x uint4
    const u64* adj8 = (const u64*)adj;
    int f0 = c * 8;             // first of this lane's 8 features
    float bb[8];
#pragma unroll
    for (int j = 0; j < 8; ++j) bb[j] = bias[f0 + j];
    float ps[8], pq[8];
#pragma unroll
    for (int j = 0; j < 8; ++j) { ps[j] = 0.f; pq[j] = 0.f; }

    for (int d = wv; d < Nn; d += NWAVES) {
        int beg = offs[d], end = offs[d + 1];
        float acc[8];
#pragma unroll
        for (int j = 0; j < 8; ++j) acc[j] = 0.f;
        int i = beg;
        for (; i + 8 <= end; i += 8) {
            u64 eA = adj8[i + g];
            u64 eB = adj8[i + 4 + g];
            uint4 hA = h4[(size_t)(uint)eA * 16 + c];
            uint4 hB = h4[(size_t)(uint)eB * 16 + c];
            float wA = __uint_as_float((uint)(eA >> 32));
            float wB = __uint_as_float((uint)(eB >> 32));
            acc[0] = fmaf(wA, bflo(hA.x), acc[0]);
            acc[1] = fmaf(wA, bfhi(hA.x), acc[1]);
            acc[2] = fmaf(wA, bflo(hA.y), acc[2]);
            acc[3] = fmaf(wA, bfhi(hA.y), acc[3]);
            acc[4] = fmaf(wA, bflo(hA.z), acc[4]);
            acc[5] = fmaf(wA, bfhi(hA.z), acc[5]);
            acc[6] = fmaf(wA, bflo(hA.w), acc[6]);
            acc[7] = fmaf(wA, bfhi(hA.w), acc[7]);
            acc[0] = fmaf(wB, bflo(hB.x), acc[0]);
            acc[1] = fmaf(wB, bfhi(hB.x), acc[1]);
            acc[2] = fmaf(wB, bflo(hB.y), acc[2]);
            acc[3] = fmaf(wB, bfhi(hB.y), acc[3]);
            acc[4] = fmaf(wB, bflo(hB.z), acc[4]);
            acc[5] = fmaf(wB, bfhi(hB.z), acc[5]);
            acc[6] = fmaf(wB, bflo(hB.w), acc[6]);
            acc[7] = fmaf(wB, bfhi(hB.w), acc[7]);
        }
        for (; i < end; i += 4) {
            int idx = i + g;
            int ok = idx < end;
            u64 e = adj8[ok ? idx : (end - 1)];
            uint4 hv = h4[(size_t)(uint)e * 16 + c];
            float w = ok ? __uint_as_float((uint)(e >> 32)) : 0.f;
            acc[0] = fmaf(w, bflo(hv.x), acc[0]);
            acc[1] = fmaf(w, bfhi(hv.x), acc[1]);
            acc[2] = fmaf(w, bflo(hv.y), acc[2]);
            acc[3] = fmaf(w, bfhi(hv.y), acc[3]);
            acc[4] = fmaf(w, bflo(hv.z), acc[4]);
            acc[5] = fmaf(w, bfhi(hv.z), acc[5]);
            acc[6] = fmaf(w, bflo(hv.w), acc[6]);
            acc[7] = fmaf(w, bfhi(hv.w), acc[7]);
        }
        // reduce across the 4 row-groups
#pragma unroll
        for (int j = 0; j < 8; ++j) {
            acc[j] += __shfl_xor(acc[j], 16);
            acc[j] += __shfl_xor(acc[j], 32);
        }
        if (g == 0) {
            float a[8];
#pragma unroll
            for (int j = 0; j < 8; ++j) a[j] = acc[j] + bb[j];
            uint4 o;
            o.x = bf16rne(a[0]) | (bf16rne(a[1]) << 16);
            o.y = bf16rne(a[2]) | (bf16rne(a[3]) << 16);
            o.z = bf16rne(a[4]) | (bf16rne(a[5]) << 16);
            o.w = bf16rne(a[6]) | (bf16rne(a[7]) << 16);
            *(uint4*)(agg + (size_t)d * 64 + c * 4) = o;
#pragma unroll
            for (int j = 0; j < 8; ++j) {
                ps[j] += a[j];
                pq[j] += a[j] * a[j];
            }
        }
    }
    if (g == 0) {
#pragma unroll
        for (int j = 0; j < 8; ++j) {
            atomicAdd(&ls[f0 + j], ps[j]);
            atomicAdd(&ls[128 + f0 + j], pq[j]);
        }
    }
    __syncthreads();
    atomicAdd(&colsum[tid], ls[tid]);
}

// ---------------- pool + linear (BN affine computed in-block) -------------

__global__ __launch_bounds__(256) void k_pool(
    const uint* __restrict__ agg, const int* __restrict__ batch,
    const float* __restrict__ cs, const float* __restrict__ gg,
    const float* __restrict__ be,
    const float* __restrict__ Wl, const float* __restrict__ bl,
    float* __restrict__ out) {
    __shared__ float scsh[256];
    int tid = threadIdx.x;
    if (tid < 128) {
        float s = cs[tid], q = cs[128 + tid];
        float m = s * (1.0f / Nn);
        float var = q * (1.0f / Nn) - m * m;
        float istd = rsqrtf(var + EPSb);
        float sc = istd * gg[tid];
        scsh[tid] = sc;
        scsh[128 + tid] = fmaf(-m, sc, be[tid]);
    }
    __syncthreads();
    int lane = tid & 63;
    int g = (blockIdx.x * blockDim.x + tid) >> 6;
    if (g >= Gg) return;
    int lo = 0, hi = Nn;
    while (lo < hi) { int mid = (lo + hi) >> 1; if (batch[mid] < g) lo = mid + 1; else hi = mid; }
    int beg = lo;
    hi = Nn;
    while (lo < hi) { int mid = (lo + hi) >> 1; if (batch[mid] < g + 1) lo = mid + 1; else hi = mid; }
    int end = lo;
    int c0 = lane * 2;
    float sc0 = scsh[c0], sh0 = scsh[128 + c0];
    float sc1 = scsh[c0 + 1], sh1 = scsh[128 + c0 + 1];
    float s0 = 0.f, s1 = 0.f;
    for (int n = beg; n < end; ++n) {
        uint v = agg[(size_t)n * 64 + lane];
        s0 += fmaxf(fmaf(bflo(v), sc0, sh0), 0.f);
        s1 += fmaxf(fmaf(bfhi(v), sc1, sh1), 0.f);
    }
    float inv = 1.0f / fmaxf((float)(end - beg), 1.0f);
    float part = (s0 * inv) * Wl[c0] + (s1 * inv) * Wl[c0 + 1];
#pragma unroll
    for (int off = 32; off; off >>= 1) part += __shfl_down(part, off);
    if (lane == 0) out[g] = part + bl[0];
}

// ---------------- launch --------------------------------------------------

extern "C" void kernel_launch(void* const* d_in, const int* in_sizes, int n_in,
                              void* d_out, int out_size, void* d_ws, size_t ws_size,
                              hipStream_t stream) {
    const float* x   = (const float*)d_in[0];
    const int*   ei  = (const int*)d_in[1];
    const int*   src = ei;
    const int*   dst = ei + Ee;
    const int*   bat = (const int*)d_in[2];
    const float* W1 = (const float*)d_in[3];
    const float* b1 = (const float*)d_in[4];
    const float* g1 = (const float*)d_in[5];
    const float* be1 = (const float*)d_in[6];
    const float* W2 = (const float*)d_in[7];
    const float* b2 = (const float*)d_in[8];
    const float* g2 = (const float*)d_in[9];
    const float* be2 = (const float*)d_in[10];
    const float* W3 = (const float*)d_in[11];
    const float* b3 = (const float*)d_in[12];
    const float* g3 = (const float*)d_in[13];
    const float* be3 = (const float*)d_in[14];
    const float* Wl = (const float*)d_in[15];
    const float* bl = (const float*)d_in[16];
    float* out = (float*)d_out;

    char* w = (char*)d_ws;
    auto alloc = [&](size_t bytes) {
        void* p = (void*)w;
        w += (bytes + 255) & ~(size_t)255;
        return p;
    };
    int*   deg    = (int*)alloc((size_t)Nn * 4);
    int*   cursor = (int*)alloc((size_t)Nn * 4);
    int*   offs   = (int*)alloc((size_t)(Nn + 1) * 4);
    int*   bsum   = (int*)alloc(256 * 4);
    float* dinv   = (float*)alloc((size_t)Nn * 4);
    float* colsum = (float*)alloc(768 * 4);   // 3 layers x 256
    uint*  Wt     = (uint*)alloc((size_t)3 * 8192 * 4);
    int2*  adj    = (int2*)alloc((size_t)(Ee + Nn) * 8);
    uint*  tmp    = (uint*)alloc((size_t)Nn * 64 * 4);   // bf16-packed h
    uint*  agg    = (uint*)alloc((size_t)Nn * 64 * 4);   // bf16-packed agg

    float* csA = colsum;        // stats of agg1 (uses g1/be1)
    float* csB = colsum + 256;  // stats of agg2 (uses g2/be2)
    float* csC = colsum + 512;  // stats of agg3 (uses g3/be3)

    // graph preprocessing + weight conversion
    k_init<<<(Nn + 255) / 256, 256, 0, stream>>>(deg, cursor, colsum);
    k_deg<<<(Ee + 255) / 256, 256, 0, stream>>>(dst, deg);
    k_scan1<<<NB_SCAN, 256, 0, stream>>>(deg, bsum);
    k_scan2<<<1, 128, 0, stream>>>(bsum);
    k_scan3<<<NB_SCAN, 256, 0, stream>>>(deg, bsum, offs, dinv);
    k_fill<<<(Ee + Nn + 255) / 256, 256, 0, stream>>>(src, dst, offs, cursor, dinv, adj);
    k_wconv3<<<96, 256, 0, stream>>>(W1, W2, W3, Wt);
    // layer 1
    k_gemm<<<GEMM_BLOCKS, 256, 0, stream>>>(x, (const uint*)0, Wt,
                                            (const float*)0, (const float*)0,
                                            (const float*)0, tmp, 0);
    k_agg<<<AGG_BLOCKS, 256, 0, stream>>>(tmp, offs, adj, b1, agg, csA);
    // layer 2
    k_gemm<<<GEMM_BLOCKS, 256, 0, stream>>>((const float*)0, agg, Wt + 8192,
                                            csA, g1, be1, tmp, 1);
    k_agg<<<AGG_BLOCKS, 256, 0, stream>>>(tmp, offs, adj, b2, agg, csB);
    // layer 3
    k_gemm<<<GEMM_BLOCKS, 256, 0, stream>>>((const float*)0, agg, Wt + 16384,
                                            csB, g2, be2, tmp, 1);
    k_agg<<<AGG_BLOCKS, 256, 0, stream>>>(tmp, offs, adj, b3, agg, csC);
    // pool + linear
    k_pool<<<(Gg * 64 + 255) / 256, 256, 0, stream>>>(agg, bat, csC, g3, be3,
                                                      Wl, bl, out);
}

// Round 10
// 595.442 us; speedup vs baseline: 1.0923x; 1.0875x over previous
//
#include <hip/hip_runtime.h>
#include <hip/hip_bf16.h>

#define Nn 100000
#define Ee 1600000
#define Hh 128
#define Gg 1000
#define EPSb 1e-5f

#define SCAN_CHUNK 1024
#define NB_SCAN 98          // ceil(100000/1024)
#define AGG_BLOCKS 2048
#define NWAVES (AGG_BLOCKS * 4)   // 8192
#define GEMM_BLOCKS 391     // x2 tiles each = 782 = ceil(100000/128)

typedef unsigned int uint;
typedef short short8 __attribute__((ext_vector_type(8)));
typedef float floatx4 __attribute__((ext_vector_type(4)));

// round-to-nearest-even f32 -> bf16 (as low 16 bits of return)
static __device__ __forceinline__ uint bf16rne(float f) {
    uint u = __float_as_uint(f);
    return (u + 0x7fffu + ((u >> 16) & 1u)) >> 16;
}
static __device__ __forceinline__ float bflo(uint u) { return __uint_as_float(u << 16); }
static __device__ __forceinline__ float bfhi(uint u) { return __uint_as_float(u & 0xffff0000u); }

// ---------------- graph preprocessing ----------------
// deg/cursor/colsum zeroed by one hipMemsetAsync; deg = in-degree only,
// the self-loop +1 is folded into the scans.

__global__ void k_deg(const int* __restrict__ dst, int* __restrict__ deg) {
    int i = blockIdx.x * blockDim.x + threadIdx.x;
    if (i < Ee) atomicAdd(&deg[dst[i]], 1);
}

__global__ void k_scan1(const int* __restrict__ deg, int* __restrict__ bsum) {
    __shared__ int ls[256];
    int t = threadIdx.x;
    int base = blockIdx.x * SCAN_CHUNK + t * 4;
    int s = 0;
#pragma unroll
    for (int j = 0; j < 4; ++j) { int i = base + j; if (i < Nn) s += deg[i] + 1; }
    ls[t] = s;
    __syncthreads();
    for (int off = 128; off; off >>= 1) {
        if (t < off) ls[t] += ls[t + off];
        __syncthreads();
    }
    if (t == 0) bsum[blockIdx.x] = ls[0];
}

// scan3: in-block scan of the 98 block sums (kills the separate scan2 launch),
// per-block exclusive scan over deg+1, emits offs and dinv.
__global__ void k_scan3(const int* __restrict__ deg, const int* __restrict__ bsum,
                        int* __restrict__ offs, float* __restrict__ dinv) {
    __shared__ int ls[256];
    __shared__ int bs[128];
    int t = threadIdx.x;
    if (t < 128) bs[t] = (t < NB_SCAN) ? bsum[t] : 0;
    int base = blockIdx.x * SCAN_CHUNK + t * 4;
    int d[4]; int s = 0;
#pragma unroll
    for (int j = 0; j < 4; ++j) {
        int i = base + j;
        d[j] = (i < Nn) ? deg[i] + 1 : 0;
        s += d[j];
    }
    ls[t] = s;
    __syncthreads();
    for (int off = 1; off < 128; off <<= 1) {
        int u = (t >= off && t < 128) ? bs[t - off] : 0;
        __syncthreads();
        if (t < 128) bs[t] += u;
        __syncthreads();
    }
    for (int off = 1; off < 256; off <<= 1) {
        int u = (t >= off) ? ls[t - off] : 0;
        __syncthreads();
        ls[t] += u;
        __syncthreads();
    }
    int blockBase = (blockIdx.x == 0) ? 0 : bs[blockIdx.x - 1];
    int run = blockBase + ls[t] - s;   // exclusive prefix for this thread
#pragma unroll
    for (int j = 0; j < 4; ++j) {
        int i = base + j;
        if (i < Nn) {
            offs[i] = run;
            dinv[i] = rsqrtf((float)d[j]);
        }
        run += d[j];
    }
    if (blockIdx.x == 0 && t == 0) offs[Nn] = Ee + Nn;
}

__global__ void k_fill(const int* __restrict__ src, const int* __restrict__ dst,
                       const int* __restrict__ offs, int* __restrict__ cursor,
                       const float* __restrict__ dinv,
                       int2* __restrict__ adj) {
    int i = blockIdx.x * blockDim.x + threadIdx.x;
    if (i >= Ee + Nn) return;
    int s, d;
    if (i < Ee) { s = src[i]; d = dst[i]; }
    else        { s = d = i - Ee; }
    int pos = offs[d] + atomicAdd(&cursor[d], 1);
    adj[pos] = make_int2(s, __float_as_int(dinv[s] * dinv[d]));
}

// ------- W conversion (all 3 layers): Wt[l][n][k/2] = bf16(W[k][n],W[k+1][n]) --

__global__ void k_wconv3(const float* __restrict__ W1, const float* __restrict__ W2,
                         const float* __restrict__ W3, uint* __restrict__ Wt) {
    int idx = blockIdx.x * blockDim.x + threadIdx.x;   // 3*8192
    if (idx >= 3 * 8192) return;
    const float* W = (idx < 8192) ? W1 : ((idx < 16384) ? W2 : W3);
    int k = idx & 8191;
    int n = k >> 6, ku = k & 63;
    uint lo = bf16rne(W[(size_t)(2 * ku) * 128 + n]);
    uint hi = bf16rne(W[(size_t)(2 * ku + 1) * 128 + n]);
    Wt[(size_t)(idx >> 13) * 8192 + n * 64 + ku] = lo | (hi << 16);
}

// ---------------- MFMA GEMM: tmp(bf16) = act(in) @ W ----------------------
// mode 0: in = fp32 x (row-major), identity activation.
// mode 1: in = row-major packed-bf16 agg; activation = relu(bn(v)), BN affine
// computed in-block from colsum + gamma + beta.
// 2 row-tiles per block: W staged once; tile-1 global loads ISSUED before
// tile-0's MFMA so HBM latency hides under compute (async-stage split).

__global__ __launch_bounds__(256, 2) void k_gemm(
    const float* __restrict__ inf, const uint* __restrict__ inb,
    const uint* __restrict__ Wtp,
    const float* __restrict__ cs, const float* __restrict__ gg,
    const float* __restrict__ be,
    uint* __restrict__ outb, int mode) {
    __shared__ uint XT[128][64];
    __shared__ uint WT[128][64];
    __shared__ float scsh[256];   // sc[128], sh[128]
    int t = threadIdx.x;
    int r = t >> 1, half = t & 1;

    if (mode && t < 128) {
        float s = cs[t], q = cs[128 + t];
        float m = s * (1.0f / Nn);
        float var = q * (1.0f / Nn) - m * m;
        float istd = rsqrtf(var + EPSb);
        float sc = istd * gg[t];
        scsh[t] = sc;
        scsh[128 + t] = fmaf(-m, sc, be[t]);
    }
    {   // stage W^T once (already packed bf16)
        const uint* sp = Wtp + (size_t)r * 64 + half * 32;
#pragma unroll
        for (int q = 0; q < 8; ++q) {
            uint4 v = *(const uint4*)(sp + q * 4);
            int g = half * 8 + q;
            *(uint4*)&WT[r][(g ^ (r & 7)) << 2] = v;
        }
    }

    float4 xf[16];   // mode-0 staging regs
    uint4  xb[8];    // mode-1 staging regs

    // ---- issue loads for tile 0 ----
    int rb0 = blockIdx.x * 128;
    {
        int grc = rb0 + r;
        if (grc >= Nn) grc = Nn - 1;
        if (mode == 0) {
            const float* sp = inf + (size_t)grc * 128 + half * 64;
#pragma unroll
            for (int q = 0; q < 8; ++q) {
                xf[2 * q]     = *(const float4*)(sp + q * 8);
                xf[2 * q + 1] = *(const float4*)(sp + q * 8 + 4);
            }
        } else {
            const uint* sp = inb + (size_t)grc * 64 + half * 32;
#pragma unroll
            for (int q = 0; q < 8; ++q) xb[q] = *(const uint4*)(sp + q * 4);
        }
    }
    __syncthreads();   // WT + scsh ready, XT free

    // ---- transform + write XT (tile 0) ----
#pragma unroll
    for (int q = 0; q < 8; ++q) {
        uint4 o;
        if (mode == 0) {
            float4 v0 = xf[2 * q], v1 = xf[2 * q + 1];
            o.x = bf16rne(v0.x) | (bf16rne(v0.y) << 16);
            o.y = bf16rne(v0.z) | (bf16rne(v0.w) << 16);
            o.z = bf16rne(v1.x) | (bf16rne(v1.y) << 16);
            o.w = bf16rne(v1.z) | (bf16rne(v1.w) << 16);
        } else {
            uint4 v = xb[q];
            int fb = half * 64 + q * 8;
            float av[8] = {bflo(v.x), bfhi(v.x), bflo(v.y), bfhi(v.y),
                           bflo(v.z), bfhi(v.z), bflo(v.w), bfhi(v.w)};
            uint oo[4];
#pragma unroll
            for (int k2 = 0; k2 < 4; ++k2) {
                float lo = fmaxf(fmaf(av[2 * k2], scsh[fb + 2 * k2],
                                      scsh[128 + fb + 2 * k2]), 0.f);
                float hi = fmaxf(fmaf(av[2 * k2 + 1], scsh[fb + 2 * k2 + 1],
                                      scsh[128 + fb + 2 * k2 + 1]), 0.f);
                oo[k2] = bf16rne(lo) | (bf16rne(hi) << 16);
            }
            o = make_uint4(oo[0], oo[1], oo[2], oo[3]);
        }
        int g = half * 8 + q;
        *(uint4*)&XT[r][(g ^ (r & 7)) << 2] = o;
    }
    __syncthreads();   // XT(tile0) ready

    int l = t & 63, w = t >> 6;
    int nb = (w >> 1) * 64;
    int fb2 = (w & 1) * 64;
    int lr = l & 15, lk = l >> 4;
    floatx4 zero = {0.f, 0.f, 0.f, 0.f};

    // ---- issue loads for tile 1 (hidden under tile-0 MFMA) ----
    int rb1 = (blockIdx.x + GEMM_BLOCKS) * 128;
    {
        int grc = rb1 + r;
        if (grc >= Nn) grc = Nn - 1;
        if (mode == 0) {
            const float* sp = inf + (size_t)grc * 128 + half * 64;
#pragma unroll
            for (int q = 0; q < 8; ++q) {
                xf[2 * q]     = *(const float4*)(sp + q * 8);
                xf[2 * q + 1] = *(const float4*)(sp + q * 8 + 4);
            }
        } else {
            const uint* sp = inb + (size_t)grc * 64 + half * 32;
#pragma unroll
            for (int q = 0; q < 8; ++q) xb[q] = *(const uint4*)(sp + q * 4);
        }
    }

    // ---- MFMA + store, tile 0 ----
    {
        floatx4 acc[4][4];
#pragma unroll
        for (int mi = 0; mi < 4; ++mi)
#pragma unroll
            for (int ni = 0; ni < 4; ++ni) acc[mi][ni] = zero;
#pragma unroll
        for (int kc = 0; kc < 4; ++kc) {
            short8 xfr[4], wfr[4];
            int g = kc * 4 + lk;
#pragma unroll
            for (int mi = 0; mi < 4; ++mi) {
                int rr = nb + mi * 16 + lr;
                xfr[mi] = *(const short8*)&XT[rr][(g ^ (rr & 7)) << 2];
            }
#pragma unroll
            for (int ni = 0; ni < 4; ++ni) {
                int rr = fb2 + ni * 16 + lr;
                wfr[ni] = *(const short8*)&WT[rr][(g ^ (rr & 7)) << 2];
            }
#pragma unroll
            for (int mi = 0; mi < 4; ++mi)
#pragma unroll
                for (int ni = 0; ni < 4; ++ni)
                    acc[mi][ni] = __builtin_amdgcn_mfma_f32_16x16x32_bf16(
                        wfr[ni], xfr[mi], acc[mi][ni], 0, 0, 0);
        }
#pragma unroll
        for (int mi = 0; mi < 4; ++mi) {
            int node = rb0 + nb + mi * 16 + lr;
            if (node < Nn) {
                uint* op = outb + (size_t)node * 64;
#pragma unroll
                for (int ni = 0; ni < 4; ++ni) {
                    int fo = fb2 + ni * 16 + lk * 4;
                    uint2 o;
                    o.x = bf16rne(acc[mi][ni][0]) | (bf16rne(acc[mi][ni][1]) << 16);
                    o.y = bf16rne(acc[mi][ni][2]) | (bf16rne(acc[mi][ni][3]) << 16);
                    *(uint2*)(op + (fo >> 1)) = o;
                }
            }
        }
    }
    __syncthreads();   // all XT(tile0) reads done

    // ---- transform + write XT (tile 1) ----
#pragma unroll
    for (int q = 0; q < 8; ++q) {
        uint4 o;
        if (mode == 0) {
            float4 v0 = xf[2 * q], v1 = xf[2 * q + 1];
            o.x = bf16rne(v0.x) | (bf16rne(v0.y) << 16);
            o.y = bf16rne(v0.z) | (bf16rne(v0.w) << 16);
            o.z = bf16rne(v1.x) | (bf16rne(v1.y) << 16);
            o.w = bf16rne(v1.z) | (bf16rne(v1.w) << 16);
        } else {
            uint4 v = xb[q];
            int fb = half * 64 + q * 8;
            float av[8] = {bflo(v.x), bfhi(v.x), bflo(v.y), bfhi(v.y),
                           bflo(v.z), bfhi(v.z), bflo(v.w), bfhi(v.w)};
            uint oo[4];
#pragma unroll
            for (int k2 = 0; k2 < 4; ++k2) {
                float lo = fmaxf(fmaf(av[2 * k2], scsh[fb + 2 * k2],
                                      scsh[128 + fb + 2 * k2]), 0.f);
                float hi = fmaxf(fmaf(av[2 * k2 + 1], scsh[fb + 2 * k2 + 1],
                                      scsh[128 + fb + 2 * k2 + 1]), 0.f);
                oo[k2] = bf16rne(lo) | (bf16rne(hi) << 16);
            }
            o = make_uint4(oo[0], oo[1], oo[2], oo[3]);
        }
        int g = half * 8 + q;
        *(uint4*)&XT[r][(g ^ (r & 7)) << 2] = o;
    }
    __syncthreads();   // XT(tile1) ready

    // ---- MFMA + store, tile 1 ----
    {
        floatx4 acc[4][4];
#pragma unroll
        for (int mi = 0; mi < 4; ++mi)
#pragma unroll
            for (int ni = 0; ni < 4; ++ni) acc[mi][ni] = zero;
#pragma unroll
        for (int kc = 0; kc < 4; ++kc) {
            short8 xfr[4], wfr[4];
            int g = kc * 4 + lk;
#pragma unroll
            for (int mi = 0; mi < 4; ++mi) {
                int rr = nb + mi * 16 + lr;
                xfr[mi] = *(const short8*)&XT[rr][(g ^ (rr & 7)) << 2];
            }
#pragma unroll
            for (int ni = 0; ni < 4; ++ni) {
                int rr = fb2 + ni * 16 + lr;
                wfr[ni] = *(const short8*)&WT[rr][(g ^ (rr & 7)) << 2];
            }
#pragma unroll
            for (int mi = 0; mi < 4; ++mi)
#pragma unroll
                for (int ni = 0; ni < 4; ++ni)
                    acc[mi][ni] = __builtin_amdgcn_mfma_f32_16x16x32_bf16(
                        wfr[ni], xfr[mi], acc[mi][ni], 0, 0, 0);
        }
#pragma unroll
        for (int mi = 0; mi < 4; ++mi) {
            int node = rb1 + nb + mi * 16 + lr;
            if (node < Nn) {
                uint* op = outb + (size_t)node * 64;
#pragma unroll
                for (int ni = 0; ni < 4; ++ni) {
                    int fo = fb2 + ni * 16 + lk * 4;
                    uint2 o;
                    o.x = bf16rne(acc[mi][ni][0]) | (bf16rne(acc[mi][ni][1]) << 16);
                    o.y = bf16rne(acc[mi][ni][2]) | (bf16rne(acc[mi][ni][3]) << 16);
                    *(uint2*)(op + (fo >> 1)) = o;
                }
            }
        }
    }
}

// ------- aggregation: agg[d] = sum_e w*h[src] + bias; BN partials -------
// Round-3/7-proven loop (measured floor: 114 us, invariant across 5 variants).

__global__ __launch_bounds__(256) void k_agg(
    const uint* __restrict__ h32, const int* __restrict__ offs,
    const int2* __restrict__ adj,
    const float* __restrict__ bias, uint* __restrict__ agg,
    float* __restrict__ colsum) {
    __shared__ float ls[256];
    int tid = threadIdx.x;
    ls[tid] = 0.f;
    __syncthreads();
    int lane = tid & 63;
    int gw = blockIdx.x * 4 + (tid >> 6);
    int nw = NWAVES;
    int c0 = lane * 2;
    float b0 = bias[c0], b1 = bias[c0 + 1];
    float ps0 = 0.f, pq0 = 0.f, ps1 = 0.f, pq1 = 0.f;
    for (int d = gw; d < Nn; d += nw) {
        int beg = offs[d], end = offs[d + 1];
        float a0 = 0.f, a1 = 0.f;
        int i = beg;
        for (; i + 8 <= end; i += 8) {
            int2 e[8];
#pragma unroll
            for (int j = 0; j < 8; ++j) e[j] = adj[i + j];
            uint hv[8];
#pragma unroll
            for (int j = 0; j < 8; ++j)
                hv[j] = h32[(size_t)e[j].x * 64 + lane];
#pragma unroll
            for (int j = 0; j < 8; ++j) {
                float w = __int_as_float(e[j].y);
                a0 = fmaf(w, bflo(hv[j]), a0);
                a1 = fmaf(w, bfhi(hv[j]), a1);
            }
        }
        for (; i < end; ++i) {
            int2 e = adj[i];
            uint hv = h32[(size_t)e.x * 64 + lane];
            float w = __int_as_float(e.y);
            a0 = fmaf(w, bflo(hv), a0);
            a1 = fmaf(w, bfhi(hv), a1);
        }
        a0 += b0; a1 += b1;
        agg[(size_t)d * 64 + lane] = bf16rne(a0) | (bf16rne(a1) << 16);
        ps0 += a0; pq0 += a0 * a0;
        ps1 += a1; pq1 += a1 * a1;
    }
    atomicAdd(&ls[c0], ps0);
    atomicAdd(&ls[c0 + 1], ps1);
    atomicAdd(&ls[128 + c0], pq0);
    atomicAdd(&ls[128 + c0 + 1], pq1);
    __syncthreads();
    atomicAdd(&colsum[tid], ls[tid]);
}

// ---------------- pool + linear (BN affine computed in-block) -------------

__global__ __launch_bounds__(256) void k_pool(
    const uint* __restrict__ agg, const int* __restrict__ batch,
    const float* __restrict__ cs, const float* __restrict__ gg,
    const float* __restrict__ be,
    const float* __restrict__ Wl, const float* __restrict__ bl,
    float* __restrict__ out) {
    __shared__ float scsh[256];
    int tid = threadIdx.x;
    if (tid < 128) {
        float s = cs[tid], q = cs[128 + tid];
        float m = s * (1.0f / Nn);
        float var = q * (1.0f / Nn) - m * m;
        float istd = rsqrtf(var + EPSb);
        float sc = istd * gg[tid];
        scsh[tid] = sc;
        scsh[128 + tid] = fmaf(-m, sc, be[tid]);
    }
    __syncthreads();
    int lane = tid & 63;
    int g = (blockIdx.x * blockDim.x + tid) >> 6;
    if (g >= Gg) return;
    int lo = 0, hi = Nn;
    while (lo < hi) { int mid = (lo + hi) >> 1; if (batch[mid] < g) lo = mid + 1; else hi = mid; }
    int beg = lo;
    hi = Nn;
    while (lo < hi) { int mid = (lo + hi) >> 1; if (batch[mid] < g + 1) lo = mid + 1; else hi = mid; }
    int end = lo;
    int c0 = lane * 2;
    float sc0 = scsh[c0], sh0 = scsh[128 + c0];
    float sc1 = scsh[c0 + 1], sh1 = scsh[128 + c0 + 1];
    float s0 = 0.f, s1 = 0.f;
    for (int n = beg; n < end; ++n) {
        uint v = agg[(size_t)n * 64 + lane];
        s0 += fmaxf(fmaf(bflo(v), sc0, sh0), 0.f);
        s1 += fmaxf(fmaf(bfhi(v), sc1, sh1), 0.f);
    }
    float inv = 1.0f / fmaxf((float)(end - beg), 1.0f);
    float part = (s0 * inv) * Wl[c0] + (s1 * inv) * Wl[c0 + 1];
#pragma unroll
    for (int off = 32; off; off >>= 1) part += __shfl_down(part, off);
    if (lane == 0) out[g] = part + bl[0];
}

// ---------------- launch --------------------------------------------------

extern "C" void kernel_launch(void* const* d_in, const int* in_sizes, int n_in,
                              void* d_out, int out_size, void* d_ws, size_t ws_size,
                              hipStream_t stream) {
    const float* x   = (const float*)d_in[0];
    const int*   ei  = (const int*)d_in[1];
    const int*   src = ei;
    const int*   dst = ei + Ee;
    const int*   bat = (const int*)d_in[2];
    const float* W1 = (const float*)d_in[3];
    const float* b1 = (const float*)d_in[4];
    const float* g1 = (const float*)d_in[5];
    const float* be1 = (const float*)d_in[6];
    const float* W2 = (const float*)d_in[7];
    const float* b2 = (const float*)d_in[8];
    const float* g2 = (const float*)d_in[9];
    const float* be2 = (const float*)d_in[10];
    const float* W3 = (const float*)d_in[11];
    const float* b3 = (const float*)d_in[12];
    const float* g3 = (const float*)d_in[13];
    const float* be3 = (const float*)d_in[14];
    const float* Wl = (const float*)d_in[15];
    const float* bl = (const float*)d_in[16];
    float* out = (float*)d_out;

    char* w = (char*)d_ws;
    auto alloc = [&](size_t bytes) {
        void* p = (void*)w;
        w += (bytes + 255) & ~(size_t)255;
        return p;
    };
    // deg, cursor, colsum first and contiguous: one memset zeroes all three
    int*   deg    = (int*)alloc((size_t)Nn * 4);
    int*   cursor = (int*)alloc((size_t)Nn * 4);
    float* colsum = (float*)alloc(768 * 4);   // 3 layers x 256
    size_t zspan  = (size_t)((char*)(colsum + 768) - (char*)deg);
    int*   offs   = (int*)alloc((size_t)(Nn + 1) * 4);
    int*   bsum   = (int*)alloc(256 * 4);
    float* dinv   = (float*)alloc((size_t)Nn * 4);
    uint*  Wt     = (uint*)alloc((size_t)3 * 8192 * 4);
    int2*  adj    = (int2*)alloc((size_t)(Ee + Nn) * 8);
    uint*  tmp    = (uint*)alloc((size_t)Nn * 64 * 4);   // bf16-packed h
    uint*  agg    = (uint*)alloc((size_t)Nn * 64 * 4);   // bf16-packed agg

    float* csA = colsum;        // stats of agg1 (uses g1/be1)
    float* csB = colsum + 256;  // stats of agg2 (uses g2/be2)
    float* csC = colsum + 512;  // stats of agg3 (uses g3/be3)

    // graph preprocessing + weight conversion
    hipMemsetAsync(deg, 0, zspan, stream);
    k_deg<<<(Ee + 255) / 256, 256, 0, stream>>>(dst, deg);
    k_scan1<<<NB_SCAN, 256, 0, stream>>>(deg, bsum);
    k_scan3<<<NB_SCAN, 256, 0, stream>>>(deg, bsum, offs, dinv);
    k_fill<<<(Ee + Nn + 255) / 256, 256, 0, stream>>>(src, dst, offs, cursor, dinv, adj);
    k_wconv3<<<96, 256, 0, stream>>>(W1, W2, W3, Wt);
    // layer 1
    k_gemm<<<GEMM_BLOCKS, 256, 0, stream>>>(x, (const uint*)0, Wt,
                                            (const float*)0, (const float*)0,
                                            (const float*)0, tmp, 0);
    k_agg<<<AGG_BLOCKS, 256, 0, stream>>>(tmp, offs, adj, b1, agg, csA);
    // layer 2
    k_gemm<<<GEMM_BLOCKS, 256, 0, stream>>>((const float*)0, agg, Wt + 8192,
                                            csA, g1, be1, tmp, 1);
    k_agg<<<AGG_BLOCKS, 256, 0, stream>>>(tmp, offs, adj, b2, agg, csB);
    // layer 3
    k_gemm<<<GEMM_BLOCKS, 256, 0, stream>>>((const float*)0, agg, Wt + 16384,
                                            csB, g2, be2, tmp, 1);
    k_agg<<<AGG_BLOCKS, 256, 0, stream>>>(tmp, offs, adj, b3, agg, csC);
    // pool + linear
    k_pool<<<(Gg * 64 + 255) / 256, 256, 0, stream>>>(agg, bat, csC, g3, be3,
                                                      Wl, bl, out);
}